// Round 1
// baseline (171.522 us; speedup 1.0000x reference)
//
#include <hip/hip_runtime.h>
#include <math.h>

#define NQ 10
#define NL 4

struct Cpx { float r, i; };

// ---- 1q complex gate on a register-bit qubit (index bits 9..6 -> r bits 3..0)
template<int RB>
__device__ __forceinline__ void gate_rbit(float ar[16], float ai[16],
                                          Cpx u00, Cpx u01, Cpx u10, Cpx u11) {
#pragma unroll
  for (int r0 = 0; r0 < 16; ++r0) {
    if ((r0 >> RB) & 1) continue;
    const int r1 = r0 | (1 << RB);
    const float a0r = ar[r0], a0i = ai[r0];
    const float a1r = ar[r1], a1i = ai[r1];
    ar[r0] = u00.r * a0r - u00.i * a0i + u01.r * a1r - u01.i * a1i;
    ai[r0] = u00.r * a0i + u00.i * a0r + u01.r * a1i + u01.i * a1r;
    ar[r1] = u10.r * a0r - u10.i * a0i + u11.r * a1r - u11.i * a1i;
    ai[r1] = u10.r * a0i + u10.i * a0r + u11.r * a1i + u11.i * a1r;
  }
}

// ---- 1q complex gate on a lane-bit qubit (index bits 5..0 -> lane bits 5..0)
template<int LB>
__device__ __forceinline__ void gate_lbit(float ar[16], float ai[16], int lane,
                                          Cpx u00, Cpx u01, Cpx u10, Cpx u11) {
  const bool hi = (lane >> LB) & 1;
  // bit==0: a' = u00*a + u01*p ; bit==1: a' = u11*a + u10*p
  const float var_ = hi ? u11.r : u00.r;
  const float vai_ = hi ? u11.i : u00.i;
  const float vbr_ = hi ? u10.r : u01.r;
  const float vbi_ = hi ? u10.i : u01.i;
#pragma unroll
  for (int r = 0; r < 16; ++r) {
    const float pr = __shfl_xor(ar[r], 1 << LB, 64);
    const float pi = __shfl_xor(ai[r], 1 << LB, 64);
    const float sr = ar[r], si = ai[r];
    ar[r] = var_ * sr - vai_ * si + vbr_ * pr - vbi_ * pi;
    ai[r] = var_ * si + vai_ * sr + vbr_ * pi + vbi_ * pr;
  }
}

// ---- CNOT: control r-bit RC, target r-bit RT (static register permutation)
template<int RC, int RT>
__device__ __forceinline__ void cnot_rr(float ar[16], float ai[16]) {
#pragma unroll
  for (int r = 0; r < 16; ++r) {
    if (((r >> RC) & 1) && !((r >> RT) & 1)) {
      const int r2 = r | (1 << RT);
      float t;
      t = ar[r]; ar[r] = ar[r2]; ar[r2] = t;
      t = ai[r]; ai[r] = ai[r2]; ai[r2] = t;
    }
  }
}

// ---- CNOT: control r-bit RC, target lane-bit LT (unconditional shuffle on half the regs)
template<int RC, int LT>
__device__ __forceinline__ void cnot_rl(float ar[16], float ai[16]) {
#pragma unroll
  for (int r = 0; r < 16; ++r) {
    if ((r >> RC) & 1) {
      ar[r] = __shfl_xor(ar[r], 1 << LT, 64);
      ai[r] = __shfl_xor(ai[r], 1 << LT, 64);
    }
  }
}

// ---- CNOT: control lane-bit LC, target lane-bit LT (shuffle + lane select)
template<int LC, int LT>
__device__ __forceinline__ void cnot_ll(float ar[16], float ai[16], int lane) {
  const bool c1 = (lane >> LC) & 1;
#pragma unroll
  for (int r = 0; r < 16; ++r) {
    const float pr = __shfl_xor(ar[r], 1 << LT, 64);
    const float pi = __shfl_xor(ai[r], 1 << LT, 64);
    ar[r] = c1 ? pr : ar[r];
    ai[r] = c1 ? pi : ai[r];
  }
}

// ---- CNOT: control lane-bit LC, target r-bit RT (lane-conditional register swap)
template<int LC, int RT>
__device__ __forceinline__ void cnot_lr(float ar[16], float ai[16], int lane) {
  const bool c1 = (lane >> LC) & 1;
#pragma unroll
  for (int r = 0; r < 16; ++r) {
    if (!((r >> RT) & 1)) {
      const int r2 = r | (1 << RT);
      const float t0r = ar[r], t1r = ar[r2];
      ar[r]  = c1 ? t1r : t0r;
      ar[r2] = c1 ? t0r : t1r;
      const float t0i = ai[r], t1i = ai[r2];
      ai[r]  = c1 ? t1i : t0i;
      ai[r2] = c1 ? t0i : t1i;
    }
  }
}

__global__ __launch_bounds__(256) void qsim_kernel(const float* __restrict__ x,
                                                   const float* __restrict__ w,
                                                   float* __restrict__ out,
                                                   int batch) {
  // ---- per-block: compute the 40 shared Rot matrices into LDS
  __shared__ float gsh[NL * NQ * 8];
  const int tid = threadIdx.x;
  if (tid < NL * NQ) {
    const float phi = w[tid * 3 + 0];
    const float th  = w[tid * 3 + 1];
    const float om  = w[tid * 3 + 2];
    float c, s, cp, sp, cm, sm;
    sincosf(0.5f * th, &s, &c);
    sincosf(-0.5f * (phi + om), &sp, &cp);   // e^{-i(phi+omega)/2}
    sincosf(0.5f * (phi - om), &sm, &cm);    // e^{ i(phi-omega)/2}
    float* g = &gsh[tid * 8];
    g[0] = cp * c;  g[1] = sp * c;    // u00 = e^{-i(phi+om)/2} c
    g[2] = -cm * s; g[3] = -sm * s;   // u01 = -e^{i(phi-om)/2} s
    g[4] = cm * s;  g[5] = -sm * s;   // u10 = e^{-i(phi-om)/2} s
    g[6] = cp * c;  g[7] = -sp * c;   // u11 = e^{i(phi+om)/2} c
  }
  __syncthreads();

  const int samp = (int)(blockIdx.x * (blockDim.x >> 6)) + (tid >> 6);
  const int lane = tid & 63;
  if (samp >= batch) return;

  // ---- encoding: state = prod_q RY(x_q)|0> is a product state; build directly.
  // amplitude index i = (r<<6) | lane ; qubit q <-> index bit (9-q)
  const float* xb = x + samp * NQ;
  float cq[NQ], sq[NQ];
#pragma unroll
  for (int q = 0; q < NQ; ++q) sincosf(0.5f * xb[q], &sq[q], &cq[q]);

  // lane-bit factors: lane bit b (0..5) <-> qubit 9-b
  float lfac = ((lane >> 0) & 1 ? sq[9] : cq[9]);
  lfac *= ((lane >> 1) & 1 ? sq[8] : cq[8]);
  lfac *= ((lane >> 2) & 1 ? sq[7] : cq[7]);
  lfac *= ((lane >> 3) & 1 ? sq[6] : cq[6]);
  lfac *= ((lane >> 4) & 1 ? sq[5] : cq[5]);
  lfac *= ((lane >> 5) & 1 ? sq[4] : cq[4]);

  float ar[16], ai[16];
#pragma unroll
  for (int r = 0; r < 16; ++r) {
    // r bit rb (0..3) <-> qubit 3-rb
    float f = lfac;
    f *= ((r >> 0) & 1 ? sq[3] : cq[3]);
    f *= ((r >> 1) & 1 ? sq[2] : cq[2]);
    f *= ((r >> 2) & 1 ? sq[1] : cq[1]);
    f *= ((r >> 3) & 1 ? sq[0] : cq[0]);
    ar[r] = f;
    ai[r] = 0.f;
  }

  // ---- layers
#pragma unroll
  for (int l = 0; l < NL; ++l) {
    const float* gl = &gsh[l * NQ * 8];
    // Rot gates: qubit q<=3 -> r bit 3-q ; qubit q>=4 -> lane bit 9-q
    {
      const float* g = gl + 0 * 8;
      gate_rbit<3>(ar, ai, {g[0],g[1]}, {g[2],g[3]}, {g[4],g[5]}, {g[6],g[7]});
    }
    {
      const float* g = gl + 1 * 8;
      gate_rbit<2>(ar, ai, {g[0],g[1]}, {g[2],g[3]}, {g[4],g[5]}, {g[6],g[7]});
    }
    {
      const float* g = gl + 2 * 8;
      gate_rbit<1>(ar, ai, {g[0],g[1]}, {g[2],g[3]}, {g[4],g[5]}, {g[6],g[7]});
    }
    {
      const float* g = gl + 3 * 8;
      gate_rbit<0>(ar, ai, {g[0],g[1]}, {g[2],g[3]}, {g[4],g[5]}, {g[6],g[7]});
    }
    {
      const float* g = gl + 4 * 8;
      gate_lbit<5>(ar, ai, lane, {g[0],g[1]}, {g[2],g[3]}, {g[4],g[5]}, {g[6],g[7]});
    }
    {
      const float* g = gl + 5 * 8;
      gate_lbit<4>(ar, ai, lane, {g[0],g[1]}, {g[2],g[3]}, {g[4],g[5]}, {g[6],g[7]});
    }
    {
      const float* g = gl + 6 * 8;
      gate_lbit<3>(ar, ai, lane, {g[0],g[1]}, {g[2],g[3]}, {g[4],g[5]}, {g[6],g[7]});
    }
    {
      const float* g = gl + 7 * 8;
      gate_lbit<2>(ar, ai, lane, {g[0],g[1]}, {g[2],g[3]}, {g[4],g[5]}, {g[6],g[7]});
    }
    {
      const float* g = gl + 8 * 8;
      gate_lbit<1>(ar, ai, lane, {g[0],g[1]}, {g[2],g[3]}, {g[4],g[5]}, {g[6],g[7]});
    }
    {
      const float* g = gl + 9 * 8;
      gate_lbit<0>(ar, ai, lane, {g[0],g[1]}, {g[2],g[3]}, {g[4],g[5]}, {g[6],g[7]});
    }
    // CNOT ring: (q,q+1) then (9,0); qubit->bit: c=q -> bit 9-q, t -> bit 9-t
    cnot_rr<3, 2>(ar, ai);        // (0,1)
    cnot_rr<2, 1>(ar, ai);        // (1,2)
    cnot_rr<1, 0>(ar, ai);        // (2,3)
    cnot_rl<0, 5>(ar, ai);        // (3,4)
    cnot_ll<5, 4>(ar, ai, lane);  // (4,5)
    cnot_ll<4, 3>(ar, ai, lane);  // (5,6)
    cnot_ll<3, 2>(ar, ai, lane);  // (6,7)
    cnot_ll<2, 1>(ar, ai, lane);  // (7,8)
    cnot_ll<1, 0>(ar, ai, lane);  // (8,9)
    cnot_lr<0, 3>(ar, ai, lane);  // (9,0)
  }

  // ---- measurement: <Z_q> = sum_i (+-) |amp_i|^2, sign from index bit (9-q)
  float p[16];
#pragma unroll
  for (int r = 0; r < 16; ++r) p[r] = ar[r] * ar[r] + ai[r] * ai[r];

  float z[NQ];
#pragma unroll
  for (int q = 0; q < 4; ++q) {
    const int rb = 3 - q;
    float acc = 0.f;
#pragma unroll
    for (int r = 0; r < 16; ++r) acc += ((r >> rb) & 1) ? -p[r] : p[r];
    z[q] = acc;
  }
  float P = 0.f;
#pragma unroll
  for (int r = 0; r < 16; ++r) P += p[r];
#pragma unroll
  for (int q = 4; q < NQ; ++q) {
    const int lb = 9 - q;
    z[q] = ((lane >> lb) & 1) ? -P : P;
  }

  // wave-wide butterfly reduce each z[q]
#pragma unroll
  for (int q = 0; q < NQ; ++q) {
    float v = z[q];
#pragma unroll
    for (int m = 1; m < 64; m <<= 1) v += __shfl_xor(v, m, 64);
    z[q] = v;
  }

  if (lane == 0) {
#pragma unroll
    for (int q = 0; q < NQ; ++q) out[samp * NQ + q] = z[q];
  }
}

extern "C" void kernel_launch(void* const* d_in, const int* in_sizes, int n_in,
                              void* d_out, int out_size, void* d_ws, size_t ws_size,
                              hipStream_t stream) {
  const float* x = (const float*)d_in[0];
  const float* w = (const float*)d_in[1];
  float* out = (float*)d_out;
  const int batch = in_sizes[0] / NQ;
  const int waves_per_block = 256 / 64;
  const int grid = (batch + waves_per_block - 1) / waves_per_block;
  hipLaunchKernelGGL(qsim_kernel, dim3(grid), dim3(256), 0, stream, x, w, out, batch);
}